// Round 7
// baseline (627.417 us; speedup 1.0000x reference)
//
#include <hip/hip_runtime.h>
#include <hip/hip_fp16.h>

// GCNRegressor: 3x GCNConv(128->128) + mean-pool + 2-layer MLP head.
// CSR-by-dst bucket sort; MFMA fp16 GEMM with register-resident B; T in
// two 64-feature slices; 2-pass gather agg (SPLIT: one dispatch per pass
// this round -- per-block code identical, pass is a kernel arg -- so the
// rocprof top-5 threshold drops to ~49us and hidden mid-size kernels
// become visible); fused mean-pool + MLP head. f32 accumulate everywhere.
//
// NOTE (rounds 1-4): 8-slice XCD-L2-residency agg variants (incl. physical
// XCC_ID work queues) all regressed; the 128B-granule gather is at the
// random-line wall (~3.5 TB/s). Round 6: LDS-staged two-level scatter
// (bucket-grouped full-line flushes) -32us, confirmed.

#define HID 128
#define NGR 512
#define NB_SHIFT 9
#define NB_W 512
#define EPB 8192

typedef __attribute__((ext_vector_type(8))) _Float16 half8;
typedef __attribute__((ext_vector_type(4))) float floatx4;

// ------------- fused W prep + histogram (independent roles) -------------
// blocks [0,48): Wt[l][n][k] = (fp16) W_l[k][n]; blocks [48,...): dst hist.

__global__ __launch_bounds__(256) void k_prep(const float* __restrict__ W0,
                                              const float* __restrict__ W1,
                                              const float* __restrict__ W2,
                                              _Float16* __restrict__ Wt,
                                              const int* __restrict__ col,
                                              int* __restrict__ ghist, int E, int nb) {
    if (blockIdx.x < 48) {
        int l = blockIdx.x >> 4;
        int chunk = blockIdx.x & 15;
        const float* W = (l == 0) ? W0 : (l == 1) ? W1 : W2;
        _Float16* D = Wt + (size_t)l * HID * HID;
        int t = threadIdx.x;
        int k  = chunk * 8 + (t >> 5);
        int n0 = (t & 31) * 4;
        float4 v = *(const float4*)(W + (size_t)k * HID + n0);
        D[(size_t)(n0 + 0) * HID + k] = (_Float16)v.x;
        D[(size_t)(n0 + 1) * HID + k] = (_Float16)v.y;
        D[(size_t)(n0 + 2) * HID + k] = (_Float16)v.z;
        D[(size_t)(n0 + 3) * HID + k] = (_Float16)v.w;
        return;
    }
    __shared__ int h[256];
    h[threadIdx.x] = 0;
    __syncthreads();
    const int nblk = gridDim.x - 48;
    for (int e = (blockIdx.x - 48) * 256 + threadIdx.x; e < E; e += nblk * 256)
        atomicAdd(&h[col[e] >> NB_SHIFT], 1);
    __syncthreads();
    int t = threadIdx.x;
    if (t < nb && h[t]) atomicAdd(&ghist[t], h[t]);
}

__global__ __launch_bounds__(256) void k_bscan(const int* __restrict__ ghist,
                                               int* __restrict__ bbase,
                                               int* __restrict__ rowptr,
                                               int N, int E, int nb) {
    __shared__ int wsum[4];
    int t = threadIdx.x, lane = t & 63, wid = t >> 6;
    int v = (t < nb) ? ghist[t] : 0;
    int sc = v;
    #pragma unroll
    for (int off = 1; off < 64; off <<= 1) {
        int u = __shfl_up(sc, off);
        if (lane >= off) sc += u;
    }
    if (lane == 63) wsum[wid] = sc;
    __syncthreads();
    int offs = 0;
    for (int w = 0; w < wid; w++) offs += wsum[w];
    int excl = offs + sc - v;
    if (t <= nb) bbase[t] = excl;
    if (t == 0) rowptr[N] = E;
}

// ------------- two-level scatter: LDS-staged, bucket-grouped flush -------
// packed entry: (src << 9) | (dst & 511). Local rank by bucket in LDS,
// one global range reservation per (block,bucket), then slot-parallel
// flush so lanes write consecutive addresses within ~32-entry runs.

__global__ __launch_bounds__(512) void k_scatter(const int* __restrict__ row,
                                                 const int* __restrict__ col,
                                                 const int* __restrict__ bbase,
                                                 int* __restrict__ bcur,
                                                 unsigned* __restrict__ sorted, int E) {
    __shared__ int hist[256];
    __shared__ int lofs[256];
    __shared__ int cur[256];
    __shared__ int gbase[256];
    __shared__ int wsum[8];
    __shared__ unsigned stage[EPB];
    __shared__ unsigned char bmap[EPB];

    const int t = threadIdx.x;
    const int base = blockIdx.x * EPB;
    if (t < 256) hist[t] = 0;
    __syncthreads();

    int dcache[EPB / 512];
    #pragma unroll
    for (int i = 0; i < EPB / 512; i++) {
        int e = base + i * 512 + t;
        if (e < E) {
            int d = col[e];
            dcache[i] = d;
            atomicAdd(&hist[d >> NB_SHIFT], 1);
        } else dcache[i] = -1;
    }
    __syncthreads();

    // 256-bin exclusive scan (512 threads, upper half contributes 0)
    int v = (t < 256) ? hist[t] : 0;
    int lane = t & 63, wid = t >> 6;
    int sc = v;
    #pragma unroll
    for (int off = 1; off < 64; off <<= 1) {
        int u = __shfl_up(sc, off);
        if (lane >= off) sc += u;
    }
    if (lane == 63) wsum[wid] = sc;
    __syncthreads();
    int offs = 0;
    for (int w = 0; w < wid; w++) offs += wsum[w];
    int e0 = offs + sc - v;
    if (t < 256) {
        lofs[t] = e0;
        cur[t]  = e0;
        if (hist[t] > 0) gbase[t] = atomicAdd(&bcur[t], hist[t]);
    }
    __syncthreads();

    // slot -> bucket map
    if (t < 256) {
        int c = hist[t], b0 = lofs[t];
        for (int k = 0; k < c; k++) bmap[b0 + k] = (unsigned char)t;
    }
    __syncthreads();

    // place into LDS stage, grouped by bucket
    #pragma unroll
    for (int i = 0; i < EPB / 512; i++) {
        int e = base + i * 512 + t;
        if (e < E) {
            int d = dcache[i];
            int b = d >> NB_SHIFT;
            int p = atomicAdd(&cur[b], 1);
            stage[p] = ((unsigned)row[e] << NB_SHIFT) | (unsigned)(d & (NB_W - 1));
        }
    }
    __syncthreads();

    // coalesced flush: consecutive lanes cover consecutive slots of a run
    int valid = E - base; if (valid > EPB) valid = EPB;
    for (int j = t; j < valid; j += 512) {
        int b = bmap[j];
        sorted[bbase[b] + gbase[b] + (j - lofs[b])] = stage[j];
    }
}

// One 512-thread block per bucket: count -> scan -> rowptr/dis/csr_src.
__global__ __launch_bounds__(512) void k_build(const unsigned* __restrict__ sorted,
                                               const int* __restrict__ bbase,
                                               int* __restrict__ csr_src,
                                               int* __restrict__ rowptr,
                                               float* __restrict__ dis, int N) {
    __shared__ int cnt[NB_W];
    __shared__ int excl[NB_W];
    __shared__ int wsum[8];
    int b = blockIdx.x, t = threadIdx.x;
    cnt[t] = 0;
    __syncthreads();
    int s0 = bbase[b], s1 = bbase[b + 1];
    for (int p = s0 + t; p < s1; p += 512)
        atomicAdd(&cnt[sorted[p] & (NB_W - 1)], 1);
    __syncthreads();
    int v = cnt[t];
    int lane = t & 63, wid = t >> 6;
    int sc = v;
    #pragma unroll
    for (int off = 1; off < 64; off <<= 1) {
        int u = __shfl_up(sc, off);
        if (lane >= off) sc += u;
    }
    if (lane == 63) wsum[wid] = sc;
    __syncthreads();
    int offs = 0;
    for (int w = 0; w < wid; w++) offs += wsum[w];
    int e0 = offs + sc - v;
    excl[t] = e0;
    int d = (b << NB_SHIFT) + t;
    if (d < N) { rowptr[d] = s0 + e0; dis[d] = rsqrtf((float)(v + 1)); }
    __syncthreads();
    for (int p = s0 + t; p < s1; p += 512) {
        unsigned sd = sorted[p];
        int q = atomicAdd(&excl[sd & (NB_W - 1)], 1);
        csr_src[s0 + q] = (int)(sd >> NB_SHIFT);
    }
}

// ---------------- GEMM: T'(2-slice fp16) = dis[row] * (A @ W) via MFMA ----
// B (whole 128x128 Wt) register-resident; wave grid-strides 16-row strips.
// C 2-slice layout: elem (r, c) at [(c>>6)*N + r]*64 + (c&63).

__device__ __forceinline__ half8 load_afrag(const float* A, int arow, int k0, int N) {
    const float* p = A + (size_t)arow * HID + k0;
    float4 v0 = *(const float4*)p;
    float4 v1 = *(const float4*)(p + 4);
    half8 h;
    h[0] = (_Float16)v0.x; h[1] = (_Float16)v0.y;
    h[2] = (_Float16)v0.z; h[3] = (_Float16)v0.w;
    h[4] = (_Float16)v1.x; h[5] = (_Float16)v1.y;
    h[6] = (_Float16)v1.z; h[7] = (_Float16)v1.w;
    return h;
}
__device__ __forceinline__ half8 load_afrag(const _Float16* A, int arow, int k0, int N) {
    return *(const half8*)(A + ((size_t)(k0 >> 6) * N + arow) * 64 + (k0 & 63));
}

template <typename AT>
__global__ __launch_bounds__(256, 2) void k_gemm(const AT* __restrict__ A,
                                                 const _Float16* __restrict__ Wt,
                                                 const float* __restrict__ dis,
                                                 __half* __restrict__ C, int N) {
    const int lane = threadIdx.x & 63;
    const int quad = lane >> 4;
    const int mc   = lane & 15;
    const int gw   = (blockIdx.x * 256 + threadIdx.x) >> 6;
    const int nw   = (gridDim.x * 256) >> 6;
    const int nstrips = (N + 15) >> 4;

    half8 b[8][4];
    #pragma unroll
    for (int j = 0; j < 8; j++)
        #pragma unroll
        for (int s = 0; s < 4; s++)
            b[j][s] = *(const half8*)(Wt + (size_t)(j * 16 + mc) * HID + s * 32 + quad * 8);

    int strip = gw;
    if (strip >= nstrips) return;

    half8 a[4];
    {
        int arow = strip * 16 + mc; if (arow >= N) arow = N - 1;
        #pragma unroll
        for (int s = 0; s < 4; s++) a[s] = load_afrag(A, arow, s * 32 + quad * 8, N);
    }

    for (; strip < nstrips; strip += nw) {
        const int row0 = strip * 16;
        const int next = strip + nw;
        half8 an[4];
        if (next < nstrips) {
            int arow = next * 16 + mc; if (arow >= N) arow = N - 1;
            #pragma unroll
            for (int s = 0; s < 4; s++) an[s] = load_afrag(A, arow, s * 32 + quad * 8, N);
        }
        floatx4 acc[8];
        #pragma unroll
        for (int j = 0; j < 8; j++) acc[j] = (floatx4){0.f, 0.f, 0.f, 0.f};
        #pragma unroll
        for (int s = 0; s < 4; s++)
            #pragma unroll
            for (int j = 0; j < 8; j++)
                acc[j] = __builtin_amdgcn_mfma_f32_16x16x32_f16(a[s], b[j][s], acc[j], 0, 0, 0);
        #pragma unroll
        for (int r = 0; r < 4; r++) {
            int gr = row0 + quad * 4 + r;
            if (gr < N) {
                float ds = dis[gr];
                #pragma unroll
                for (int j = 0; j < 8; j++)
                    C[((size_t)(j >> 2) * N + gr) * 64 + (j & 3) * 16 + mc] =
                        __float2half(ds * acc[j][r]);
            }
        }
        #pragma unroll
        for (int s = 0; s < 4; s++) a[s] = an[s];
    }
}

// ---------------- aggregation (one dispatch per feature-slice pass) ------
// Per-block code identical to the proven r0 design; pass is now a kernel
// arg (diagnostic split: halves each dispatch so rocprof top-5 exposes
// any hidden 49-98us kernel). Half-wave per dst: p = edge slot (4),
// h = float4 slot (8). 16-edge unroll (24 VGPR / high occupancy).

__device__ __forceinline__ void add8(float* acc, float4 r) {
    __half2* h = (__half2*)&r;
    #pragma unroll
    for (int k = 0; k < 4; k++) {
        float2 v = __half22float2(h[k]);
        acc[2 * k]     += v.x;
        acc[2 * k + 1] += v.y;
    }
}

__global__ __launch_bounds__(256) void k_agg(const __half* __restrict__ T,
                                             const float* __restrict__ dis,
                                             const int* __restrict__ rowptr,
                                             const int* __restrict__ csr_src,
                                             const float* __restrict__ bias,
                                             __half* __restrict__ out, int N, int pass) {
    const int nbi  = blockIdx.x;
    const int g    = threadIdx.x >> 5;
    const int l    = threadIdx.x & 31;
    const int p    = l >> 3;
    const int h    = l & 7;
    const int n = nbi * 8 + g;
    if (n >= N) return;

    const float4* T4 = (const float4*)(T + (size_t)pass * N * 64);

    float acc[8] = {};

    int e  = rowptr[n];
    int e1 = rowptr[n + 1];
    for (; e + 16 <= e1; e += 16) {
        int s0 = csr_src[e + p];
        int s1 = csr_src[e + 4 + p];
        int s2 = csr_src[e + 8 + p];
        int s3 = csr_src[e + 12 + p];
        float4 r0 = T4[(size_t)s0 * 8 + h];
        float4 r1 = T4[(size_t)s1 * 8 + h];
        float4 r2 = T4[(size_t)s2 * 8 + h];
        float4 r3 = T4[(size_t)s3 * 8 + h];
        add8(acc, r0); add8(acc, r1); add8(acc, r2); add8(acc, r3);
    }
    for (; e + 4 <= e1; e += 4) {
        int s = csr_src[e + p];
        add8(acc, T4[(size_t)s * 8 + h]);
    }
    if (e + p < e1) {
        int s = csr_src[e + p];
        add8(acc, T4[(size_t)s * 8 + h]);
    }
    if (p == 0) add8(acc, T4[(size_t)n * 8 + h]);   // self-loop

    #pragma unroll
    for (int k = 0; k < 8; k++) {
        acc[k] += __shfl_xor(acc[k], 8, 64);
        acc[k] += __shfl_xor(acc[k], 16, 64);
    }

    if (p == 0) {
        float dn = dis[n];
        half8 o;
        #pragma unroll
        for (int k = 0; k < 8; k++) {
            float v = fmaf(dn, acc[k], bias[pass * 64 + h * 8 + k]);
            o[k] = (_Float16)fmaxf(v, 0.f);
        }
        *(half8*)((_Float16*)out + ((size_t)pass * N + n) * 64 + h * 8) = o;
    }
}

// ---------------- fused mean-pool + MLP head ----------------

__device__ __forceinline__ int lbound(const int* __restrict__ batch, int N, int g) {
    int lo = 0, hi = N;
    while (lo < hi) {
        int mid = (lo + hi) >> 1;
        if (batch[mid] < g) lo = mid + 1; else hi = mid;
    }
    return lo;
}

__global__ __launch_bounds__(256) void k_poolmlp(const __half* __restrict__ hbuf,
                                                 const int* __restrict__ batch,
                                                 const float* __restrict__ Wm0,
                                                 const float* __restrict__ bm0,
                                                 const float* __restrict__ Wm1,
                                                 const float* __restrict__ bm1,
                                                 float* __restrict__ out, int N) {
    __shared__ float red[2048];
    __shared__ float g[HID];
    const int gr = blockIdx.x, t = threadIdx.x;
    const int s = lbound(batch, N, gr), e = lbound(batch, N, gr + 1);

    const int rg = t >> 4, cl = t & 15;
    const _Float16* base = (const _Float16*)hbuf
        + (size_t)(cl >> 3) * N * 64 + (size_t)(cl & 7) * 8;
    float acc[8] = {};
    for (int r = s + rg; r < e; r += 16) {
        half8 v = *(const half8*)(base + (size_t)r * 64);
        #pragma unroll
        for (int k = 0; k < 8; k++) acc[k] += (float)v[k];
    }
    #pragma unroll
    for (int k = 0; k < 8; k++) red[t * 8 + k] = acc[k];
    __syncthreads();
    if (t < 128) {
        int cl2 = t >> 3, k = t & 7;
        float sm = 0.f;
        #pragma unroll
        for (int rg2 = 0; rg2 < 16; rg2++) sm += red[(rg2 * 16 + cl2) * 8 + k];
        int feat = (cl2 & 7) * 8 + k + ((cl2 >> 3) ? 64 : 0);
        g[feat] = sm / fmaxf((float)(e - s), 1.f);
    }
    __syncthreads();

    const int j = t & 127, hh = t >> 7;
    float a = 0.f;
    for (int k = hh * 64; k < hh * 64 + 64; k++)
        a = fmaf(g[k], Wm0[(size_t)k * HID + j], a);
    red[hh * 128 + j] = a;
    __syncthreads();

    if (t < 128) {
        float h1 = fmaxf(bm0[j] + red[j] + red[128 + j], 0.f);
        float z = h1 * Wm1[j];
        #pragma unroll
        for (int off = 32; off > 0; off >>= 1) z += __shfl_xor(z, off, 64);
        if ((t & 63) == 0) red[1024 + (t >> 6)] = z;
    }
    __syncthreads();
    if (t == 0) out[gr] = red[1024] + red[1025] + bm1[0];
}

// ---------------- launch ----------------

extern "C" void kernel_launch(void* const* d_in, const int* in_sizes, int n_in,
                              void* d_out, int out_size, void* d_ws, size_t ws_size,
                              hipStream_t stream) {
    const float* x     = (const float*)d_in[0];
    const int*   ei    = (const int*)d_in[1];
    const int*   batch = (const int*)d_in[3];
    const float* W0 = (const float*)d_in[4],  *b0 = (const float*)d_in[5];
    const float* W1 = (const float*)d_in[6],  *b1 = (const float*)d_in[7];
    const float* W2 = (const float*)d_in[8],  *b2 = (const float*)d_in[9];
    const float* Wm0 = (const float*)d_in[10], *bm0 = (const float*)d_in[11];
    const float* Wm1 = (const float*)d_in[12], *bm1 = (const float*)d_in[13];

    const int N = in_sizes[0] / HID;
    const int E = in_sizes[1] / 2;
    const int nb = (N + NB_W - 1) >> NB_SHIFT;
    const int* row  = ei;
    const int* colI = ei + E;

    char* w = (char*)d_ws;
    auto carve = [&](size_t bytes) {
        void* p = (void*)w;
        w += (bytes + 255) & ~(size_t)255;
        return p;
    };
    int*      ibuf    = (int*)     carve(512 * 4);
    int*      bbase   = (int*)     carve(257 * 4);
    float*    dis     = (float*)   carve((size_t)N * 4);
    int*      rowptr  = (int*)     carve((size_t)(N + 1) * 4);
    unsigned* sorted  = (unsigned*)carve((size_t)E * 4);
    int*      csr_src = (int*)     carve((size_t)E * 4);
    _Float16* wth     = (_Float16*)carve((size_t)3 * HID * HID * 2);
    __half*   bufT    = (__half*)  carve((size_t)N * HID * 2);
    __half*   bufA    = (__half*)  carve((size_t)N * HID * 2);
    __half*   bufB    = (__half*)  carve((size_t)N * HID * 2);

    int* ghist = ibuf;
    int* bcur  = ibuf + 256;

    hipMemsetAsync(ibuf, 0, 512 * 4, stream);
    k_prep   <<<48 + 512, 256, 0, stream>>>(W0, W1, W2, wth, colI, ghist, E, nb);
    k_bscan  <<<1, 256, 0, stream>>>(ghist, bbase, rowptr, N, E, nb);
    k_scatter<<<(E + EPB - 1) / EPB, 512, 0, stream>>>(row, colI, bbase, bcur, sorted, E);
    k_build  <<<nb, 512, 0, stream>>>(sorted, bbase, csr_src, rowptr, dis, N);

    dim3 gg(512);
    dim3 ga((N + 7) / 8);                   // one dispatch per pass now

    k_gemm<float>    <<<gg, 256, 0, stream>>>(x, wth, dis, bufT, N);
    k_agg            <<<ga, 256, 0, stream>>>(bufT, dis, rowptr, csr_src, b0, bufA, N, 0);
    k_agg            <<<ga, 256, 0, stream>>>(bufT, dis, rowptr, csr_src, b0, bufA, N, 1);
    k_gemm<_Float16> <<<gg, 256, 0, stream>>>((const _Float16*)bufA, wth + HID * HID, dis, bufT, N);
    k_agg            <<<ga, 256, 0, stream>>>(bufT, dis, rowptr, csr_src, b1, bufB, N, 0);
    k_agg            <<<ga, 256, 0, stream>>>(bufT, dis, rowptr, csr_src, b1, bufB, N, 1);
    k_gemm<_Float16> <<<gg, 256, 0, stream>>>((const _Float16*)bufB, wth + 2 * HID * HID, dis, bufT, N);
    k_agg            <<<ga, 256, 0, stream>>>(bufT, dis, rowptr, csr_src, b2, bufA, N, 0);
    k_agg            <<<ga, 256, 0, stream>>>(bufT, dis, rowptr, csr_src, b2, bufA, N, 1);

    k_poolmlp<<<NGR, 256, 0, stream>>>(bufA, batch, Wm0, bm0, Wm1, bm1, (float*)d_out, N);
}

// Round 8
// 592.254 us; speedup vs baseline: 1.0594x; 1.0594x over previous
//
#include <hip/hip_runtime.h>
#include <hip/hip_fp16.h>

// GCNRegressor: 3x GCNConv(128->128) + mean-pool + 2-layer MLP head.
// CSR-by-dst bucket sort (256-wide buckets for 2x build parallelism);
// MFMA fp16 GEMM with register-resident B; T in two 64-feature slices;
// 2-pass gather agg combined in one dispatch (r7 split cost +28us: ramp/
// tail at half-size dispatches); fused mean-pool + MLP head. f32 accum.
//
// NOTE (rounds 1-4): 8-slice XCD-L2-residency agg variants (incl. physical
// XCC_ID work queues) all regressed; the 128B-granule gather is at the
// random-line wall (~3.5 TB/s). Round 6: LDS-staged two-level scatter
// (bucket-grouped full-line flushes) -32us, confirmed. Round 7 diagnostic:
// no non-agg dispatch exceeds 55us.

#define HID 128
#define NGR 512
#define NB_SHIFT 8
#define NB_W 256
#define NBINS 512
#define EPB 8192

typedef __attribute__((ext_vector_type(8))) _Float16 half8;
typedef __attribute__((ext_vector_type(4))) float floatx4;

// ------------- fused W prep + histogram (independent roles) -------------
// blocks [0,48): Wt[l][n][k] = (fp16) W_l[k][n]; blocks [48,...): dst hist.

__global__ __launch_bounds__(256) void k_prep(const float* __restrict__ W0,
                                              const float* __restrict__ W1,
                                              const float* __restrict__ W2,
                                              _Float16* __restrict__ Wt,
                                              const int* __restrict__ col,
                                              int* __restrict__ ghist, int E, int nb) {
    if (blockIdx.x < 48) {
        int l = blockIdx.x >> 4;
        int chunk = blockIdx.x & 15;
        const float* W = (l == 0) ? W0 : (l == 1) ? W1 : W2;
        _Float16* D = Wt + (size_t)l * HID * HID;
        int t = threadIdx.x;
        int k  = chunk * 8 + (t >> 5);
        int n0 = (t & 31) * 4;
        float4 v = *(const float4*)(W + (size_t)k * HID + n0);
        D[(size_t)(n0 + 0) * HID + k] = (_Float16)v.x;
        D[(size_t)(n0 + 1) * HID + k] = (_Float16)v.y;
        D[(size_t)(n0 + 2) * HID + k] = (_Float16)v.z;
        D[(size_t)(n0 + 3) * HID + k] = (_Float16)v.w;
        return;
    }
    __shared__ int h[NBINS];
    int t = threadIdx.x;
    h[t] = 0; h[t + 256] = 0;
    __syncthreads();
    const int nblk = gridDim.x - 48;
    for (int e = (blockIdx.x - 48) * 256 + t; e < E; e += nblk * 256)
        atomicAdd(&h[col[e] >> NB_SHIFT], 1);
    __syncthreads();
    if (t < nb && h[t]) atomicAdd(&ghist[t], h[t]);
    if (t + 256 < nb && h[t + 256]) atomicAdd(&ghist[t + 256], h[t + 256]);
}

__global__ __launch_bounds__(512) void k_bscan(const int* __restrict__ ghist,
                                               int* __restrict__ bbase,
                                               int* __restrict__ rowptr,
                                               int N, int E, int nb) {
    __shared__ int wsum[8];
    int t = threadIdx.x, lane = t & 63, wid = t >> 6;
    int v = (t < nb) ? ghist[t] : 0;
    int sc = v;
    #pragma unroll
    for (int off = 1; off < 64; off <<= 1) {
        int u = __shfl_up(sc, off);
        if (lane >= off) sc += u;
    }
    if (lane == 63) wsum[wid] = sc;
    __syncthreads();
    int offs = 0;
    for (int w = 0; w < wid; w++) offs += wsum[w];
    int excl = offs + sc - v;
    if (t <= nb) bbase[t] = excl;
    if (t == 0) rowptr[N] = E;
}

// ------------- two-level scatter: LDS-staged, bucket-grouped flush -------
// packed entry: (src << 8) | (dst & 255). Local rank by bucket in LDS,
// one global range reservation per (block,bucket), then slot-parallel
// flush so lanes write consecutive addresses within bucket runs.

__global__ __launch_bounds__(512) void k_scatter(const int* __restrict__ row,
                                                 const int* __restrict__ col,
                                                 const int* __restrict__ bbase,
                                                 int* __restrict__ bcur,
                                                 unsigned* __restrict__ sorted, int E) {
    __shared__ int hist[NBINS];
    __shared__ int lofs[NBINS];
    __shared__ int cur[NBINS];
    __shared__ int gbase[NBINS];
    __shared__ int wsum[8];
    __shared__ unsigned stage[EPB];
    __shared__ unsigned short bmap[EPB];

    const int t = threadIdx.x;
    const int base = blockIdx.x * EPB;
    hist[t] = 0;
    __syncthreads();

    int dcache[EPB / 512];
    #pragma unroll
    for (int i = 0; i < EPB / 512; i++) {
        int e = base + i * 512 + t;
        if (e < E) {
            int d = col[e];
            dcache[i] = d;
            atomicAdd(&hist[d >> NB_SHIFT], 1);
        } else dcache[i] = -1;
    }
    __syncthreads();

    // 512-bin exclusive scan
    int v = hist[t];
    int lane = t & 63, wid = t >> 6;
    int sc = v;
    #pragma unroll
    for (int off = 1; off < 64; off <<= 1) {
        int u = __shfl_up(sc, off);
        if (lane >= off) sc += u;
    }
    if (lane == 63) wsum[wid] = sc;
    __syncthreads();
    int offs = 0;
    for (int w = 0; w < wid; w++) offs += wsum[w];
    int e0 = offs + sc - v;
    lofs[t] = e0;
    cur[t]  = e0;
    if (v > 0) gbase[t] = atomicAdd(&bcur[t], v);
    __syncthreads();

    // slot -> bucket map
    {
        int c = hist[t], b0 = lofs[t];
        for (int k = 0; k < c; k++) bmap[b0 + k] = (unsigned short)t;
    }
    __syncthreads();

    // place into LDS stage, grouped by bucket
    #pragma unroll
    for (int i = 0; i < EPB / 512; i++) {
        int e = base + i * 512 + t;
        if (e < E) {
            int d = dcache[i];
            int b = d >> NB_SHIFT;
            int p = atomicAdd(&cur[b], 1);
            stage[p] = ((unsigned)row[e] << NB_SHIFT) | (unsigned)(d & (NB_W - 1));
        }
    }
    __syncthreads();

    // coalesced flush: consecutive lanes cover consecutive slots of a run
    int valid = E - base; if (valid > EPB) valid = EPB;
    for (int j = t; j < valid; j += 512) {
        int b = bmap[j];
        sorted[bbase[b] + gbase[b] + (j - lofs[b])] = stage[j];
    }
}

// One 512-thread block per 256-dst bucket: count -> scan -> csr_src.
__global__ __launch_bounds__(512) void k_build(const unsigned* __restrict__ sorted,
                                               const int* __restrict__ bbase,
                                               int* __restrict__ csr_src,
                                               int* __restrict__ rowptr,
                                               float* __restrict__ dis, int N) {
    __shared__ int cnt[NB_W];
    __shared__ int excl[NB_W];
    __shared__ int wsum[8];
    int b = blockIdx.x, t = threadIdx.x;
    if (t < NB_W) cnt[t] = 0;
    __syncthreads();
    int s0 = bbase[b], s1 = bbase[b + 1];
    for (int p = s0 + t; p < s1; p += 512)
        atomicAdd(&cnt[sorted[p] & (NB_W - 1)], 1);
    __syncthreads();
    int v = (t < NB_W) ? cnt[t] : 0;
    int lane = t & 63, wid = t >> 6;
    int sc = v;
    #pragma unroll
    for (int off = 1; off < 64; off <<= 1) {
        int u = __shfl_up(sc, off);
        if (lane >= off) sc += u;
    }
    if (lane == 63) wsum[wid] = sc;
    __syncthreads();
    int offs = 0;
    for (int w = 0; w < wid; w++) offs += wsum[w];
    int e0 = offs + sc - v;
    if (t < NB_W) {
        excl[t] = e0;
        int d = (b << NB_SHIFT) + t;
        if (d < N) { rowptr[d] = s0 + e0; dis[d] = rsqrtf((float)(v + 1)); }
    }
    __syncthreads();
    for (int p = s0 + t; p < s1; p += 512) {
        unsigned sd = sorted[p];
        int q = atomicAdd(&excl[sd & (NB_W - 1)], 1);
        csr_src[s0 + q] = (int)(sd >> NB_SHIFT);
    }
}

// ---------------- GEMM: T'(2-slice fp16) = dis[row] * (A @ W) via MFMA ----
// B (whole 128x128 Wt) register-resident; wave grid-strides 16-row strips.
// C 2-slice layout: elem (r, c) at [(c>>6)*N + r]*64 + (c&63).

__device__ __forceinline__ half8 load_afrag(const float* A, int arow, int k0, int N) {
    const float* p = A + (size_t)arow * HID + k0;
    float4 v0 = *(const float4*)p;
    float4 v1 = *(const float4*)(p + 4);
    half8 h;
    h[0] = (_Float16)v0.x; h[1] = (_Float16)v0.y;
    h[2] = (_Float16)v0.z; h[3] = (_Float16)v0.w;
    h[4] = (_Float16)v1.x; h[5] = (_Float16)v1.y;
    h[6] = (_Float16)v1.z; h[7] = (_Float16)v1.w;
    return h;
}
__device__ __forceinline__ half8 load_afrag(const _Float16* A, int arow, int k0, int N) {
    return *(const half8*)(A + ((size_t)(k0 >> 6) * N + arow) * 64 + (k0 & 63));
}

template <typename AT>
__global__ __launch_bounds__(256, 2) void k_gemm(const AT* __restrict__ A,
                                                 const _Float16* __restrict__ Wt,
                                                 const float* __restrict__ dis,
                                                 __half* __restrict__ C, int N) {
    const int lane = threadIdx.x & 63;
    const int quad = lane >> 4;
    const int mc   = lane & 15;
    const int gw   = (blockIdx.x * 256 + threadIdx.x) >> 6;
    const int nw   = (gridDim.x * 256) >> 6;
    const int nstrips = (N + 15) >> 4;

    half8 b[8][4];
    #pragma unroll
    for (int j = 0; j < 8; j++)
        #pragma unroll
        for (int s = 0; s < 4; s++)
            b[j][s] = *(const half8*)(Wt + (size_t)(j * 16 + mc) * HID + s * 32 + quad * 8);

    int strip = gw;
    if (strip >= nstrips) return;

    half8 a[4];
    {
        int arow = strip * 16 + mc; if (arow >= N) arow = N - 1;
        #pragma unroll
        for (int s = 0; s < 4; s++) a[s] = load_afrag(A, arow, s * 32 + quad * 8, N);
    }

    for (; strip < nstrips; strip += nw) {
        const int row0 = strip * 16;
        const int next = strip + nw;
        half8 an[4];
        if (next < nstrips) {
            int arow = next * 16 + mc; if (arow >= N) arow = N - 1;
            #pragma unroll
            for (int s = 0; s < 4; s++) an[s] = load_afrag(A, arow, s * 32 + quad * 8, N);
        }
        floatx4 acc[8];
        #pragma unroll
        for (int j = 0; j < 8; j++) acc[j] = (floatx4){0.f, 0.f, 0.f, 0.f};
        #pragma unroll
        for (int s = 0; s < 4; s++)
            #pragma unroll
            for (int j = 0; j < 8; j++)
                acc[j] = __builtin_amdgcn_mfma_f32_16x16x32_f16(a[s], b[j][s], acc[j], 0, 0, 0);
        #pragma unroll
        for (int r = 0; r < 4; r++) {
            int gr = row0 + quad * 4 + r;
            if (gr < N) {
                float ds = dis[gr];
                #pragma unroll
                for (int j = 0; j < 8; j++)
                    C[((size_t)(j >> 2) * N + gr) * 64 + (j & 3) * 16 + mc] =
                        __float2half(ds * acc[j][r]);
            }
        }
        #pragma unroll
        for (int s = 0; s < 4; s++) a[s] = an[s];
    }
}

// ---------------- aggregation (2 feature-slice passes, XCD affinity) ------
// Flat grid; pass = (blockIdx>>2)&1 so blockIdx%8 in {0..3} -> slice 0 and
// {4..7} -> slice 1. Half-wave per dst: p = edge slot (4), h = float4
// slot (8). 16-edge unroll (24 VGPR / high occupancy).

__device__ __forceinline__ void add8(float* acc, float4 r) {
    __half2* h = (__half2*)&r;
    #pragma unroll
    for (int k = 0; k < 4; k++) {
        float2 v = __half22float2(h[k]);
        acc[2 * k]     += v.x;
        acc[2 * k + 1] += v.y;
    }
}

__global__ __launch_bounds__(256) void k_agg(const __half* __restrict__ T,
                                             const float* __restrict__ dis,
                                             const int* __restrict__ rowptr,
                                             const int* __restrict__ csr_src,
                                             const float* __restrict__ bias,
                                             __half* __restrict__ out, int N) {
    const int b    = blockIdx.x;
    const int pass = (b >> 2) & 1;
    const int nbi  = ((b >> 3) << 2) | (b & 3);
    const int g    = threadIdx.x >> 5;
    const int l    = threadIdx.x & 31;
    const int p    = l >> 3;
    const int h    = l & 7;
    const int n = nbi * 8 + g;
    if (n >= N) return;

    const float4* T4 = (const float4*)(T + (size_t)pass * N * 64);

    float acc[8] = {};

    int e  = rowptr[n];
    int e1 = rowptr[n + 1];
    for (; e + 16 <= e1; e += 16) {
        int s0 = csr_src[e + p];
        int s1 = csr_src[e + 4 + p];
        int s2 = csr_src[e + 8 + p];
        int s3 = csr_src[e + 12 + p];
        float4 r0 = T4[(size_t)s0 * 8 + h];
        float4 r1 = T4[(size_t)s1 * 8 + h];
        float4 r2 = T4[(size_t)s2 * 8 + h];
        float4 r3 = T4[(size_t)s3 * 8 + h];
        add8(acc, r0); add8(acc, r1); add8(acc, r2); add8(acc, r3);
    }
    for (; e + 4 <= e1; e += 4) {
        int s = csr_src[e + p];
        add8(acc, T4[(size_t)s * 8 + h]);
    }
    if (e + p < e1) {
        int s = csr_src[e + p];
        add8(acc, T4[(size_t)s * 8 + h]);
    }
    if (p == 0) add8(acc, T4[(size_t)n * 8 + h]);   // self-loop

    #pragma unroll
    for (int k = 0; k < 8; k++) {
        acc[k] += __shfl_xor(acc[k], 8, 64);
        acc[k] += __shfl_xor(acc[k], 16, 64);
    }

    if (p == 0) {
        float dn = dis[n];
        half8 o;
        #pragma unroll
        for (int k = 0; k < 8; k++) {
            float v = fmaf(dn, acc[k], bias[pass * 64 + h * 8 + k]);
            o[k] = (_Float16)fmaxf(v, 0.f);
        }
        *(half8*)((_Float16*)out + ((size_t)pass * N + n) * 64 + h * 8) = o;
    }
}

// ---------------- fused mean-pool + MLP head ----------------

__device__ __forceinline__ int lbound(const int* __restrict__ batch, int N, int g) {
    int lo = 0, hi = N;
    while (lo < hi) {
        int mid = (lo + hi) >> 1;
        if (batch[mid] < g) lo = mid + 1; else hi = mid;
    }
    return lo;
}

__global__ __launch_bounds__(256) void k_poolmlp(const __half* __restrict__ hbuf,
                                                 const int* __restrict__ batch,
                                                 const float* __restrict__ Wm0,
                                                 const float* __restrict__ bm0,
                                                 const float* __restrict__ Wm1,
                                                 const float* __restrict__ bm1,
                                                 float* __restrict__ out, int N) {
    __shared__ float red[2048];
    __shared__ float g[HID];
    const int gr = blockIdx.x, t = threadIdx.x;
    const int s = lbound(batch, N, gr), e = lbound(batch, N, gr + 1);

    const int rg = t >> 4, cl = t & 15;
    const _Float16* base = (const _Float16*)hbuf
        + (size_t)(cl >> 3) * N * 64 + (size_t)(cl & 7) * 8;
    float acc[8] = {};
    for (int r = s + rg; r < e; r += 16) {
        half8 v = *(const half8*)(base + (size_t)r * 64);
        #pragma unroll
        for (int k = 0; k < 8; k++) acc[k] += (float)v[k];
    }
    #pragma unroll
    for (int k = 0; k < 8; k++) red[t * 8 + k] = acc[k];
    __syncthreads();
    if (t < 128) {
        int cl2 = t >> 3, k = t & 7;
        float sm = 0.f;
        #pragma unroll
        for (int rg2 = 0; rg2 < 16; rg2++) sm += red[(rg2 * 16 + cl2) * 8 + k];
        int feat = (cl2 & 7) * 8 + k + ((cl2 >> 3) ? 64 : 0);
        g[feat] = sm / fmaxf((float)(e - s), 1.f);
    }
    __syncthreads();

    const int j = t & 127, hh = t >> 7;
    float a = 0.f;
    for (int k = hh * 64; k < hh * 64 + 64; k++)
        a = fmaf(g[k], Wm0[(size_t)k * HID + j], a);
    red[hh * 128 + j] = a;
    __syncthreads();

    if (t < 128) {
        float h1 = fmaxf(bm0[j] + red[j] + red[128 + j], 0.f);
        float z = h1 * Wm1[j];
        #pragma unroll
        for (int off = 32; off > 0; off >>= 1) z += __shfl_xor(z, off, 64);
        if ((t & 63) == 0) red[1024 + (t >> 6)] = z;
    }
    __syncthreads();
    if (t == 0) out[gr] = red[1024] + red[1025] + bm1[0];
}

// ---------------- launch ----------------

extern "C" void kernel_launch(void* const* d_in, const int* in_sizes, int n_in,
                              void* d_out, int out_size, void* d_ws, size_t ws_size,
                              hipStream_t stream) {
    const float* x     = (const float*)d_in[0];
    const int*   ei    = (const int*)d_in[1];
    const int*   batch = (const int*)d_in[3];
    const float* W0 = (const float*)d_in[4],  *b0 = (const float*)d_in[5];
    const float* W1 = (const float*)d_in[6],  *b1 = (const float*)d_in[7];
    const float* W2 = (const float*)d_in[8],  *b2 = (const float*)d_in[9];
    const float* Wm0 = (const float*)d_in[10], *bm0 = (const float*)d_in[11];
    const float* Wm1 = (const float*)d_in[12], *bm1 = (const float*)d_in[13];

    const int N = in_sizes[0] / HID;
    const int E = in_sizes[1] / 2;
    const int nb = (N + NB_W - 1) >> NB_SHIFT;
    const int* row  = ei;
    const int* colI = ei + E;

    char* w = (char*)d_ws;
    auto carve = [&](size_t bytes) {
        void* p = (void*)w;
        w += (bytes + 255) & ~(size_t)255;
        return p;
    };
    int*      ibuf    = (int*)     carve(1024 * 4);
    int*      bbase   = (int*)     carve(513 * 4);
    float*    dis     = (float*)   carve((size_t)N * 4);
    int*      rowptr  = (int*)     carve((size_t)(N + 1) * 4);
    unsigned* sorted  = (unsigned*)carve((size_t)E * 4);
    int*      csr_src = (int*)     carve((size_t)E * 4);
    _Float16* wth     = (_Float16*)carve((size_t)3 * HID * HID * 2);
    __half*   bufT    = (__half*)  carve((size_t)N * HID * 2);
    __half*   bufA    = (__half*)  carve((size_t)N * HID * 2);
    __half*   bufB    = (__half*)  carve((size_t)N * HID * 2);

    int* ghist = ibuf;
    int* bcur  = ibuf + 512;

    hipMemsetAsync(ibuf, 0, 1024 * 4, stream);
    k_prep   <<<48 + 512, 256, 0, stream>>>(W0, W1, W2, wth, colI, ghist, E, nb);
    k_bscan  <<<1, 512, 0, stream>>>(ghist, bbase, rowptr, N, E, nb);
    k_scatter<<<(E + EPB - 1) / EPB, 512, 0, stream>>>(row, colI, bbase, bcur, sorted, E);
    k_build  <<<nb, 512, 0, stream>>>(sorted, bbase, csr_src, rowptr, dis, N);

    dim3 gg(512);
    const int nblk4 = (((N + 7) / 8) + 3) & ~3;   // node-blocks, padded to x4
    dim3 ga(2 * nblk4);

    k_gemm<float>    <<<gg, 256, 0, stream>>>(x, wth, dis, bufT, N);
    k_agg            <<<ga, 256, 0, stream>>>(bufT, dis, rowptr, csr_src, b0, bufA, N);
    k_gemm<_Float16> <<<gg, 256, 0, stream>>>((const _Float16*)bufA, wth + HID * HID, dis, bufT, N);
    k_agg            <<<ga, 256, 0, stream>>>(bufT, dis, rowptr, csr_src, b1, bufB, N);
    k_gemm<_Float16> <<<gg, 256, 0, stream>>>((const _Float16*)bufB, wth + 2 * HID * HID, dis, bufT, N);
    k_agg            <<<ga, 256, 0, stream>>>(bufT, dis, rowptr, csr_src, b2, bufA, N);

    k_poolmlp<<<NGR, 256, 0, stream>>>(bufA, batch, Wm0, bm0, Wm1, bm1, (float*)d_out, N);
}